// Round 15
// baseline (206.672 us; speedup 1.0000x reference)
//
#include <hip/hip_runtime.h>
#include <math.h>

// B,C,T = 32,1024,1024; beta=0.95; thr=1.0; sigma=10.5
#define B_     32
#define C_     1024
#define T_     1024
#define RT     92                    // tap radius (|d|>92 cannot flip any f32 spike; r2-r14)
#define CT     64                    // channels per block
#define TT     64                    // time chunk
#define KC     16                    // channels per thread (halves DS reads/output)
#define NTY    4                     // 4 waves, 256 threads
#define WOFF   (RT + KC - 1)         // 107: tap idx = d + 107, real idx in [15,199]
#define NWT    216                   // tap floats (54 quads, rows 0..53 pads)
#define NCOLS  (CT + 2*RT)           // 248 staged channel columns
#define XSTR   252                   // xsT row stride (dwords); cols 248..251 = tap pad
#define ISTR   65                    // I-strip row stride (dwords): conflict-free
#define NF4    (NCOLS * (TT/4))      // 3968 staged float4s per chunk

// numpy-faithful f32 tap (identical op sequence; exp via correctly-rounded f64).
__device__ __forceinline__ float tap_value(float s, int d) {
    float u    = __fdiv_rn((float)d, s);
    float t1   = __fmul_rn(-0.5f, u);
    float t2   = __fmul_rn(t1, u);
    float e    = (float)exp((double)t2);
    float den  = __fmul_rn(s, sqrtf(6.2831854820251465f));
    float coef = __fdiv_rn(1.0f, den);
    return __fmul_rn(coef, e);
}

#define EL(v, i) ((i) == 0 ? (v).x : (i) == 1 ? (v).y : (i) == 2 ? (v).z : (v).w)
// il in [0,26] -> select from 7 tap quads (compile-time)
#define SEL7(il, W0, W1, W2, W3, W4, W5, W6)                                    \
    ((il) < 4 ? EL(W0, (il)) : (il) < 8 ? EL(W1, (il) - 4)                      \
     : (il) < 12 ? EL(W2, (il) - 8) : (il) < 16 ? EL(W3, (il) - 12)             \
     : (il) < 20 ? EL(W4, (il) - 16) : (il) < 24 ? EL(W5, (il) - 20)            \
     : EL(W6, (il) - 24))

// One source column (pass-relative cc): 16 FMAs, taps compile-time selected.
#define COL16(XV, CC, W0, W1, W2, W3, W4, W5, W6)                               \
    do {                                                                        \
        float x1_ = EL(XV, (CC) & 3);                                           \
        _Pragma("unroll")                                                       \
        for (int k = 0; k < KC; ++k) {                                          \
            const int il_ = (CC) + (KC - 1) - k;                                \
            acc[k] = fmaf(SEL7(il_, W0, W1, W2, W3, W4, W5, W6), x1_, acc[k]);  \
        }                                                                       \
    } while (0)

// Pass p: cols 12p..12p+11 (ascending j), tap quads 3p..3p+6, x quads 3p..3p+2.
#define PASS(P)                                                                 \
    do {                                                                        \
        float4 w0 = TAPQ(3*(P)+0), w1 = TAPQ(3*(P)+1), w2 = TAPQ(3*(P)+2);      \
        float4 w3 = TAPQ(3*(P)+3), w4 = TAPQ(3*(P)+4), w5 = TAPQ(3*(P)+5);      \
        float4 w6 = TAPQ(3*(P)+6);                                              \
        float4 a0 = xq[3*(P)+0], a1 = xq[3*(P)+1], a2 = xq[3*(P)+2];            \
        COL16(a0, 0,  w0,w1,w2,w3,w4,w5,w6); COL16(a0, 1,  w0,w1,w2,w3,w4,w5,w6); \
        COL16(a0, 2,  w0,w1,w2,w3,w4,w5,w6); COL16(a0, 3,  w0,w1,w2,w3,w4,w5,w6); \
        COL16(a1, 4,  w0,w1,w2,w3,w4,w5,w6); COL16(a1, 5,  w0,w1,w2,w3,w4,w5,w6); \
        COL16(a1, 6,  w0,w1,w2,w3,w4,w5,w6); COL16(a1, 7,  w0,w1,w2,w3,w4,w5,w6); \
        COL16(a2, 8,  w0,w1,w2,w3,w4,w5,w6); COL16(a2, 9,  w0,w1,w2,w3,w4,w5,w6); \
        COL16(a2, 10, w0,w1,w2,w3,w4,w5,w6); COL16(a2, 11, w0,w1,w2,w3,w4,w5,w6); \
    } while (0)

// Last pass: cols 192..199, tap quads 48..53 (il <= 22), x quads 48..49.
#define PASSL()                                                                 \
    do {                                                                        \
        float4 w0 = TAPQ(48), w1 = TAPQ(49), w2 = TAPQ(50);                     \
        float4 w3 = TAPQ(51), w4 = TAPQ(52), w5 = TAPQ(53);                     \
        float4 a0 = xq[48], a1 = xq[49];                                        \
        COL16(a0, 0, w0,w1,w2,w3,w4,w5,w5); COL16(a0, 1, w0,w1,w2,w3,w4,w5,w5); \
        COL16(a0, 2, w0,w1,w2,w3,w4,w5,w5); COL16(a0, 3, w0,w1,w2,w3,w4,w5,w5); \
        COL16(a1, 4, w0,w1,w2,w3,w4,w5,w5); COL16(a1, 5, w0,w1,w2,w3,w4,w5,w5); \
        COL16(a1, 6, w0,w1,w2,w3,w4,w5,w5); COL16(a1, 7, w0,w1,w2,w3,w4,w5,w5); \
    } while (0)

// KC=16: 256 threads, 4 waves; 8 waves/CU (2/SIMD) -> up to 256 VGPR budget.
// Wave ty owns channels c0+16ty..+15; lanes tx<16 run the LIF scan.
__global__ __launch_bounds__(256)
__attribute__((amdgpu_waves_per_eu(2, 4))) void snn_v15(
    const float* __restrict__ x, const float* __restrict__ sigma,
    float* __restrict__ out)
{
    __shared__ __align__(16) float xsT[TT * XSTR];       // 64512 B (incl. tap pads)
    __shared__ __align__(16) float IsS[NTY * KC * ISTR]; // 16640 B (total 81152)

    const int tx   = threadIdx.x;      // t lane 0..63
    const int ty   = threadIdx.y;      // wave 0..3
    const int flat = ty * 64 + tx;     // 0..255
    const int b    = blockIdx.y;
    const int c0   = blockIdx.x * CT;
    const int rb   = ty * KC;          // first local channel of this wave

    const float* xb = x   + (size_t)b * ((size_t)C_ * T_);
    float*       ob = out + (size_t)b * ((size_t)C_ * T_);

    // ---- taps into xsT row pads (rows 0..53, cols 248..251) ----
    if (flat < NWT) {
        int d = flat - WOFF;
        xsT[(flat >> 2) * XSTR + 248 + (flat & 3)] =
            (d >= -RT && d <= RT) ? tap_value(sigma[0], d) : 0.0f;
    }

    // ---- register staging (T14): 16 quads/thread ----
    float4 stg[16];                    // statically indexed only (rule #20)

#define STAGE_LOAD(T0)                                                          \
    _Pragma("unroll")                                                           \
    for (int i = 0; i < 16; ++i) {                                              \
        int e = flat + i * 256;                                                 \
        float4 v = make_float4(0.f, 0.f, 0.f, 0.f);                             \
        if (e < NF4) {                                                          \
            int r = e >> 4, c4 = e & 15;                                        \
            int c = c0 - RT + r;                                                \
            if (c >= 0 && c < C_)                                               \
                v = *(const float4*)(xb + (size_t)c * T_ + (T0) + c4 * 4);      \
        }                                                                       \
        stg[i] = v;                                                             \
    }

#define STAGE_WRITE()                                                           \
    _Pragma("unroll")                                                           \
    for (int i = 0; i < 16; ++i) {                                              \
        int e = flat + i * 256;                                                 \
        if (e < NF4) {                                                          \
            int r = e >> 4, c4 = e & 15;                                        \
            xsT[(4 * c4 + 0) * XSTR + r] = stg[i].x;                            \
            xsT[(4 * c4 + 1) * XSTR + r] = stg[i].y;                            \
            xsT[(4 * c4 + 2) * XSTR + r] = stg[i].z;                            \
            xsT[(4 * c4 + 3) * XSTR + r] = stg[i].w;                            \
        }                                                                       \
    }

#define TAPQ(Q) (*(const float4*)(xsT + (Q) * XSTR + 248))

    STAGE_LOAD(0);

    float mem = 0.0f;                  // channel c0+rb+tx (lanes tx<16)
    float rc  = 0.0f;                  // carried reset (= previous spike)
    float* strip = IsS + ty * (KC * ISTR);
    const float4* xq = (const float4*)(xsT + tx * XSTR + rb);

#pragma unroll 1
    for (int kk = 0; kk < T_ / TT; ++kk) {
        STAGE_WRITE();          // chunk kk -> xsT (waits its own vmcnt)
        __syncthreads();        // xsT + taps ready for all waves

        if (kk < T_ / TT - 1) { STAGE_LOAD((kk + 1) * TT); }  // lands by next write

        // ---- conv: 50 b128 x-reads, 54 uniform tap quads, 3200 FMA/thread ----
        float acc[KC];
#pragma unroll
        for (int k = 0; k < KC; ++k) acc[k] = 0.0f;

        PASS(0);  PASS(1);  PASS(2);  PASS(3);
        PASS(4);  PASS(5);  PASS(6);  PASS(7);
        PASS(8);  PASS(9);  PASS(10); PASS(11);
        PASS(12); PASS(13); PASS(14); PASS(15);
        PASSL();                          // ascending j, exact f32 chain per output

        // I = x - conv -> wave-local strip (own x = cols rb+92..rb+107)
        {
            float4 xo0 = xq[23], xo1 = xq[24], xo2 = xq[25], xo3 = xq[26];
            strip[ 0 * ISTR + tx] = __fsub_rn(xo0.x, acc[0]);
            strip[ 1 * ISTR + tx] = __fsub_rn(xo0.y, acc[1]);
            strip[ 2 * ISTR + tx] = __fsub_rn(xo0.z, acc[2]);
            strip[ 3 * ISTR + tx] = __fsub_rn(xo0.w, acc[3]);
            strip[ 4 * ISTR + tx] = __fsub_rn(xo1.x, acc[4]);
            strip[ 5 * ISTR + tx] = __fsub_rn(xo1.y, acc[5]);
            strip[ 6 * ISTR + tx] = __fsub_rn(xo1.z, acc[6]);
            strip[ 7 * ISTR + tx] = __fsub_rn(xo1.w, acc[7]);
            strip[ 8 * ISTR + tx] = __fsub_rn(xo2.x, acc[8]);
            strip[ 9 * ISTR + tx] = __fsub_rn(xo2.y, acc[9]);
            strip[10 * ISTR + tx] = __fsub_rn(xo2.z, acc[10]);
            strip[11 * ISTR + tx] = __fsub_rn(xo2.w, acc[11]);
            strip[12 * ISTR + tx] = __fsub_rn(xo3.x, acc[12]);
            strip[13 * ISTR + tx] = __fsub_rn(xo3.y, acc[13]);
            strip[14 * ISTR + tx] = __fsub_rn(xo3.z, acc[14]);
            strip[15 * ISTR + tx] = __fsub_rn(xo3.w, acc[15]);
        }

        // ---- wave-local LIF scan (lanes tx<16; channel c0+rb+tx) ----
        // strip is SAME-WAVE data (in-order DS, compiler lgkmcnt). reset =
        // RN(soft + RN(1-soft)) == 1.0f exactly for soft in (0,0.5): the atan
        // surrogate is bit-exactly a compare; reset_{t+1} == spike_t.
        if (tx < KC) {
            float m = mem, r = rc;
            const float* srow = strip + tx * ISTR;
            float* orow = ob + (size_t)(c0 + rb + tx) * T_ + (size_t)kk * TT;
#pragma unroll 4
            for (int q = 0; q < TT / 4; ++q) {
                float4 s;
#pragma unroll
                for (int qq = 0; qq < 4; ++qq) {
                    float Ivv = srow[4 * q + qq];
                    m = __fsub_rn(__fadd_rn(__fmul_rn(0.95f, m), Ivv), r);
                    float sp = (m > 1.0f) ? 1.0f : 0.0f;
                    r = sp;
                    if (qq == 0) s.x = sp; else if (qq == 1) s.y = sp;
                    else if (qq == 2) s.z = sp; else s.w = sp;
                }
                *(float4*)(orow + 4 * q) = s;
            }
            mem = m; rc = r;
        }
        __syncthreads();        // xsT WAR: all waves' reads done before next write
    }
#undef STAGE_LOAD
#undef STAGE_WRITE
#undef TAPQ
}

extern "C" void kernel_launch(void* const* d_in, const int* in_sizes, int n_in,
                              void* d_out, int out_size, void* d_ws, size_t ws_size,
                              hipStream_t stream) {
    const float* x     = (const float*)d_in[0];   // [32,1024,1024] f32
    const float* sigma = (const float*)d_in[1];   // [1] f32
    float* out = (float*)d_out;

    dim3 grid(C_ / CT, B_);   // (16, 32) = 512 blocks, 2/CU
    dim3 block(64, NTY);      // 256 threads, 4 waves

    snn_v15<<<grid, block, 0, stream>>>(x, sigma, out);
}

// Round 16
// 177.422 us; speedup vs baseline: 1.1649x; 1.1649x over previous
//
#include <hip/hip_runtime.h>
#include <math.h>

// B,C,T = 32,1024,1024; beta=0.95; thr=1.0; sigma=10.5
#define B_     32
#define C_     1024
#define T_     1024
#define RT     92                    // tap radius (|d|>92 cannot flip any f32 spike; r2-r15)
#define CT     64                    // channels per block
#define TT     64                    // time chunk
#define KC     8                     // channels per thread group
#define NTY    8                     // 8 waves, 512 threads
#define WOFF   (RT + KC - 1)         // 99: tap idx = d + 99, idx in [0,198]
#define NWT    200                   // tap floats (50 quads, rows 0..49 pads)
#define NCOLS  (CT + 2*RT)           // 248 staged channel columns
#define XSTR   252                   // xsT row stride (dwords); cols 248..251 = tap pad
#define ISTR   68                    // I-strip row stride (dwords): 16B-aligned rows,
                                     //   conflict-free b128 scan reads
#define NF4    (NCOLS * (TT/4))     // 3968 staged float4s per chunk
#define NSQ0   19                    // first SGPR-resident tap quad
#define NSQN   12                    // 12 quads = 48 taps (il 76..123, d in [-23,24])

// numpy-faithful f32 tap (identical op sequence; exp via correctly-rounded f64).
__device__ __forceinline__ float tap_value(float s, int d) {
    float u    = __fdiv_rn((float)d, s);
    float t1   = __fmul_rn(-0.5f, u);
    float t2   = __fmul_rn(t1, u);
    float e    = (float)exp((double)t2);
    float den  = __fmul_rn(s, sqrtf(6.2831854820251465f));
    float coef = __fdiv_rn(1.0f, den);
    return __fmul_rn(coef, e);
}

#define EL(v, i) ((i) == 0 ? (v).x : (i) == 1 ? (v).y : (i) == 2 ? (v).z : (v).w)
#define SEL5(il, T0, T1, T2, T3, T4)                                            \
    ((il) < 4 ? EL(T0, (il)) : (il) < 8 ? EL(T1, (il) - 4)                      \
     : (il) < 12 ? EL(T2, (il) - 8) : (il) < 16 ? EL(T3, (il) - 12)             \
     : EL(T4, (il) - 16))

// One source column (pass-relative cc): 8 FMAs, taps compile-time selected.
#define COL(XV, CC, T0, T1, T2, T3, T4)                                         \
    do {                                                                        \
        float x1_ = EL(XV, (CC) & 3);                                           \
        _Pragma("unroll")                                                       \
        for (int k = 0; k < KC; ++k) {                                          \
            const int il_ = (CC) + 7 - k;                                       \
            acc[k] = fmaf(SEL5(il_, T0, T1, T2, T3, T4), x1_, acc[k]);          \
        }                                                                       \
    } while (0)

// Tap quad Q: SGPR-resident for Q in [NSQ0, NSQ0+NSQN), else LDS pad read.
// Q is always compile-time -> dead branch folds, sgq index static (rule #20).
#define GETQ(Q)                                                                 \
    (((Q) >= NSQ0 && (Q) < NSQ0 + NSQN)                                         \
         ? sgq[((Q) >= NSQ0 && (Q) < NSQ0 + NSQN) ? (Q) - NSQ0 : 0]             \
         : TAPQ(Q))

// Pass over cols QB*4..QB*4+11 (QB=3p): FIRST pull next pass's 3 x-quads and
// 3 tap-quads into rotating names (SGPR quads cost nothing), THEN 12 ascending
// columns with the current names.
#define PASSX(QB, T0, T1, T2, T3, T4, L0, L1, L2, XA, XB, XC, YA, YB, YC, DOLD) \
    do {                                                                        \
        if (DOLD) {                                                             \
            YA = xq[(QB) + 3]; YB = xq[(QB) + 4]; YC = xq[(QB) + 5];            \
            L0 = GETQ((QB) + 5); L1 = GETQ((QB) + 6); L2 = GETQ((QB) + 7);      \
        }                                                                       \
        COL(XA, 0, T0, T1, T2, T3, T4);  COL(XA, 1, T0, T1, T2, T3, T4);        \
        COL(XA, 2, T0, T1, T2, T3, T4);  COL(XA, 3, T0, T1, T2, T3, T4);        \
        COL(XB, 4, T0, T1, T2, T3, T4);  COL(XB, 5, T0, T1, T2, T3, T4);        \
        COL(XB, 6, T0, T1, T2, T3, T4);  COL(XB, 7, T0, T1, T2, T3, T4);        \
        COL(XC, 8, T0, T1, T2, T3, T4);  COL(XC, 9, T0, T1, T2, T3, T4);        \
        COL(XC, 10, T0, T1, T2, T3, T4); COL(XC, 11, T0, T1, T2, T3, T4);       \
    } while (0)

__global__ __launch_bounds__(512, 4) void snn_v16(
    const float* __restrict__ x, const float* __restrict__ sigma,
    float* __restrict__ out)
{
    __shared__ __align__(16) float xsT[TT * XSTR];       // 64512 B (incl. tap pads)
    __shared__ __align__(16) float IsS[NTY * KC * ISTR]; // 17408 B (total 81920 = 2/CU)

    const int tx   = threadIdx.x;      // t lane 0..63
    const int ty   = threadIdx.y;      // wave 0..7
    const int flat = ty * 64 + tx;
    const int b    = blockIdx.y;
    const int c0   = blockIdx.x * CT;
    const int rb   = ty * KC;

    const float* xb = x   + (size_t)b * ((size_t)C_ * T_);
    float*       ob = out + (size_t)b * ((size_t)C_ * T_);

    // ---- taps into xsT row pads (rows 0..49, cols 248..251) ----
    if (flat < NWT) {
        int d = flat - WOFF;
        xsT[(flat >> 2) * XSTR + 248 + (flat & 3)] =
            (d >= -RT && d <= RT) ? tap_value(sigma[0], d) : 0.0f;
    }

    // ---- register staging (proven path): (r = chan col, c4 = t-quad) ----
    float4 stg[2][4];                  // statically indexed only (rule #20)
    const int rB  = (flat >> 2);       // 0..127
    const int c4B = (flat & 3);        // 0..3

#define STAGE_LOAD(T0)                                                          \
    _Pragma("unroll")                                                           \
    for (int i1 = 0; i1 < 2; ++i1) {                                            \
        _Pragma("unroll")                                                       \
        for (int i2 = 0; i2 < 4; ++i2) {                                        \
            int r  = rB + 128 * i1;                                             \
            int c4 = c4B + 4 * i2;                                              \
            int c  = c0 - RT + r;                                               \
            float4 v = make_float4(0.f, 0.f, 0.f, 0.f);                         \
            if (r < NCOLS && c >= 0 && c < C_)                                  \
                v = *(const float4*)(xb + (size_t)c * T_ + (T0) + c4 * 4);      \
            stg[i1][i2] = v;                                                    \
        }                                                                       \
    }

#define STAGE_WRITE()                                                           \
    _Pragma("unroll")                                                           \
    for (int i1 = 0; i1 < 2; ++i1) {                                            \
        _Pragma("unroll")                                                       \
        for (int i2 = 0; i2 < 4; ++i2) {                                        \
            int r  = rB + 128 * i1;                                             \
            int c4 = c4B + 4 * i2;                                              \
            if (r < NCOLS) {                                                    \
                xsT[(4 * c4 + 0) * XSTR + r] = stg[i1][i2].x;                   \
                xsT[(4 * c4 + 1) * XSTR + r] = stg[i1][i2].y;                   \
                xsT[(4 * c4 + 2) * XSTR + r] = stg[i1][i2].z;                   \
                xsT[(4 * c4 + 3) * XSTR + r] = stg[i1][i2].w;                   \
            }                                                                   \
        }                                                                       \
    }

#define TAPQ(Q) (*(const float4*)(xsT + (Q) * XSTR + 248))

    STAGE_LOAD(0);
    __syncthreads();                   // taps visible to all waves

    // ---- 48 central taps -> SGPRs, once per kernel (readfirstlane forces
    //      scalar residence; values are wave-uniform by construction) ----
    float4 sgq[NSQN];                  // statically indexed only
#pragma unroll
    for (int i = 0; i < NSQN; ++i) {
        float4 q = TAPQ(NSQ0 + i);
        sgq[i].x = __int_as_float(__builtin_amdgcn_readfirstlane(__float_as_int(q.x)));
        sgq[i].y = __int_as_float(__builtin_amdgcn_readfirstlane(__float_as_int(q.y)));
        sgq[i].z = __int_as_float(__builtin_amdgcn_readfirstlane(__float_as_int(q.z)));
        sgq[i].w = __int_as_float(__builtin_amdgcn_readfirstlane(__float_as_int(q.w)));
    }

    float mem = 0.0f;                  // channel c0+rb+tx (lanes tx<8)
    float rc  = 0.0f;                  // carried reset (= previous spike)
    float* strip = IsS + ty * (KC * ISTR);
    const float4* xq = (const float4*)(xsT + tx * XSTR + rb);

#pragma unroll 1
    for (int kk = 0; kk < T_ / TT; ++kk) {
        STAGE_WRITE();          // chunk kk -> xsT (waits its own vmcnt)
        __syncthreads();        // xsT ready for all waves

        if (kk < T_ / TT - 1) { STAGE_LOAD((kk + 1) * TT); }  // lands by next write

        float acc[KC];
#pragma unroll
        for (int k = 0; k < KC; ++k) acc[k] = 0.0f;

        // ---- prologue: pass-0 operands ----
        float4 n0 = GETQ(0), n1 = GETQ(1), n2 = GETQ(2), n3 = GETQ(3), n4 = GETQ(4);
        float4 x0 = xq[0], x1 = xq[1], x2 = xq[2];
        float4 n5, n6, n7, x3, x4, x5;

        // ---- 16 software-pipelined passes (rotating names; ascending j) ----
        PASSX(0,  n0,n1,n2,n3,n4, n5,n6,n7, x0,x1,x2, x3,x4,x5, 1);
        PASSX(3,  n3,n4,n5,n6,n7, n0,n1,n2, x3,x4,x5, x0,x1,x2, 1);
        PASSX(6,  n6,n7,n0,n1,n2, n3,n4,n5, x0,x1,x2, x3,x4,x5, 1);
        PASSX(9,  n1,n2,n3,n4,n5, n6,n7,n0, x3,x4,x5, x0,x1,x2, 1);
        PASSX(12, n4,n5,n6,n7,n0, n1,n2,n3, x0,x1,x2, x3,x4,x5, 1);
        PASSX(15, n7,n0,n1,n2,n3, n4,n5,n6, x3,x4,x5, x0,x1,x2, 1);
        PASSX(18, n2,n3,n4,n5,n6, n7,n0,n1, x0,x1,x2, x3,x4,x5, 1);
        PASSX(21, n5,n6,n7,n0,n1, n2,n3,n4, x3,x4,x5, x0,x1,x2, 1);
        PASSX(24, n0,n1,n2,n3,n4, n5,n6,n7, x0,x1,x2, x3,x4,x5, 1);
        PASSX(27, n3,n4,n5,n6,n7, n0,n1,n2, x3,x4,x5, x0,x1,x2, 1);
        PASSX(30, n6,n7,n0,n1,n2, n3,n4,n5, x0,x1,x2, x3,x4,x5, 1);
        PASSX(33, n1,n2,n3,n4,n5, n6,n7,n0, x3,x4,x5, x0,x1,x2, 1);
        PASSX(36, n4,n5,n6,n7,n0, n1,n2,n3, x0,x1,x2, x3,x4,x5, 1);
        PASSX(39, n7,n0,n1,n2,n3, n4,n5,n6, x3,x4,x5, x0,x1,x2, 1);
        PASSX(42, n2,n3,n4,n5,n6, n7,n0,n1, x0,x1,x2, x3,x4,x5, 1);
        PASSX(45, n5,n6,n7,n0,n1, n2,n3,n4, x3,x4,x5, x0,x1,x2, 0);

        // I = x - conv -> wave-local strip (no cross-wave hazard)
        {
            float4 xo0 = xq[RT / 4];        // own x, cols rb+92..95
            float4 xo1 = xq[RT / 4 + 1];    // cols rb+96..99
            strip[0 * ISTR + tx] = __fsub_rn(xo0.x, acc[0]);
            strip[1 * ISTR + tx] = __fsub_rn(xo0.y, acc[1]);
            strip[2 * ISTR + tx] = __fsub_rn(xo0.z, acc[2]);
            strip[3 * ISTR + tx] = __fsub_rn(xo0.w, acc[3]);
            strip[4 * ISTR + tx] = __fsub_rn(xo1.x, acc[4]);
            strip[5 * ISTR + tx] = __fsub_rn(xo1.y, acc[5]);
            strip[6 * ISTR + tx] = __fsub_rn(xo1.z, acc[6]);
            strip[7 * ISTR + tx] = __fsub_rn(xo1.w, acc[7]);
        }

        // ---- wave-local LIF scan (lanes tx<8; channel c0+rb+tx) ----
        // strip is SAME-WAVE data (in-order DS, compiler lgkmcnt); rows are
        // 16B-aligned (ISTR=68) so the 4 t-reads merge into one ds_read_b128.
        // reset = RN(soft + RN(1-soft)) == 1.0f exactly for soft in (0,0.5):
        // the atan surrogate is bit-exactly a compare; reset_{t+1} == spike_t.
        if (tx < KC) {
            float m = mem, r = rc;
            const float4* srow4 = (const float4*)(strip + tx * ISTR);
            float* orow = ob + (size_t)(c0 + rb + tx) * T_ + (size_t)kk * TT;
#pragma unroll 4
            for (int q = 0; q < TT / 4; ++q) {
                float4 Iq = srow4[q];
                float4 s;
#pragma unroll
                for (int qq = 0; qq < 4; ++qq) {
                    float Ivv = EL(Iq, qq);
                    m = __fsub_rn(__fadd_rn(__fmul_rn(0.95f, m), Ivv), r);
                    float sp = (m > 1.0f) ? 1.0f : 0.0f;
                    r = sp;
                    if (qq == 0) s.x = sp; else if (qq == 1) s.y = sp;
                    else if (qq == 2) s.z = sp; else s.w = sp;
                }
                *(float4*)(orow + 4 * q) = s;
            }
            mem = m; rc = r;
        }
        __syncthreads();        // xsT WAR: all waves' reads done before next write
    }
#undef STAGE_LOAD
#undef STAGE_WRITE
#undef TAPQ
}

extern "C" void kernel_launch(void* const* d_in, const int* in_sizes, int n_in,
                              void* d_out, int out_size, void* d_ws, size_t ws_size,
                              hipStream_t stream) {
    const float* x     = (const float*)d_in[0];   // [32,1024,1024] f32
    const float* sigma = (const float*)d_in[1];   // [1] f32
    float* out = (float*)d_out;

    dim3 grid(C_ / CT, B_);   // (16, 32) = 512 blocks, 2/CU
    dim3 block(64, NTY);      // 512 threads, 8 waves

    snn_v16<<<grid, block, 0, stream>>>(x, sigma, out);
}